// Round 1
// baseline (524.221 us; speedup 1.0000x reference)
//
#include <hip/hip_runtime.h>

#define B_ 2
#define S_ 2048
#define D_ 1024
#define H_ 16
#define DH_ 64
#define DF_ 4096
#define M_ (B_*S_)   // 4096

typedef __bf16 bf16_t;
typedef __attribute__((ext_vector_type(8))) __bf16 bf16x8;
typedef __attribute__((ext_vector_type(4))) float f32x4;

__device__ inline f32x4 mfma16(bf16x8 a, bf16x8 b, f32x4 c){
  return __builtin_amdgcn_mfma_f32_16x16x32_bf16(a, b, c, 0, 0, 0);
}

// ---- repack Wq/Wk/Wv [H][D][DH] fp32 -> [N=h*DH+dh][K=d] bf16 ----
__global__ __launch_bounds__(256) void repack_qkv_k(const float* __restrict__ w,
                                                    bf16_t* __restrict__ o){
  int idx = blockIdx.x * 256 + threadIdx.x;     // over D_*D_
  int n = idx >> 10, d = idx & (D_ - 1);
  o[idx] = (bf16_t)w[((size_t)(n >> 6) * D_ + d) * DH_ + (n & 63)];
}

// ---- transpose fp32 [K][N] -> bf16 [N][K] ----
__global__ __launch_bounds__(256) void transpose_f2b_k(const float* __restrict__ in,
                                                       bf16_t* __restrict__ out,
                                                       int K, int N){
  __shared__ float t[32][33];
  int kb = blockIdx.x * 32, nb = blockIdx.y * 32;
  for (int i = threadIdx.y; i < 32; i += 8)
    t[i][threadIdx.x] = in[(size_t)(kb + i) * N + nb + threadIdx.x];
  __syncthreads();
  for (int i = threadIdx.y; i < 32; i += 8)
    out[(size_t)(nb + i) * K + kb + threadIdx.x] = (bf16_t)t[threadIdx.x][i];
}

// ---- LayerNorm fp32 row -> bf16 (matches ref: mean, biased std, /(std+1e-9)) ----
__global__ __launch_bounds__(256) void ln_k(const float* __restrict__ x,
                                            const float* __restrict__ g,
                                            const float* __restrict__ o,
                                            bf16_t* __restrict__ out){
  int row = blockIdx.x;
  const float* xr = x + (size_t)row * D_;
  f32x4 v = *((const f32x4*)xr + threadIdx.x);
  float s  = v[0] + v[1] + v[2] + v[3];
  float sq = v[0]*v[0] + v[1]*v[1] + v[2]*v[2] + v[3]*v[3];
  #pragma unroll
  for (int off = 1; off < 64; off <<= 1){
    s  += __shfl_xor(s, off);
    sq += __shfl_xor(sq, off);
  }
  __shared__ float ss[4], ssq[4];
  int wid = threadIdx.x >> 6;
  if ((threadIdx.x & 63) == 0){ ss[wid] = s; ssq[wid] = sq; }
  __syncthreads();
  s  = ss[0] + ss[1] + ss[2] + ss[3];
  sq = ssq[0] + ssq[1] + ssq[2] + ssq[3];
  float mean = s * (1.0f / D_);
  float var  = fmaxf(sq * (1.0f / D_) - mean * mean, 0.0f);
  float inv  = 1.0f / (sqrtf(var) + 1e-9f);
  int c = threadIdx.x * 4;
  bf16_t* orow = out + (size_t)row * D_;
  #pragma unroll
  for (int j = 0; j < 4; j++)
    orow[c + j] = (bf16_t)(g[c + j] * ((v[j] - mean) * inv) + o[c + j]);
}

// ---- GEMM: C[M,N] = A[M,K](bf16) @ Bt[N,K](bf16)^T, fp32 acc, fused epilogues ----
// EPI 0: Q/K out bf16 [bh][s][dh]   EPI 1: V out bf16 transposed [bh][dh][s]
// EPI 2: fp32 out = acc+bias+resid  EPI 3: bf16 out = relu(acc+bias)
// EPI 4: fp32 out = acc+bias+resid
template<int EPI>
__global__ __launch_bounds__(256) void gemm_k(const bf16_t* __restrict__ A,
                                              const bf16_t* __restrict__ Bt,
                                              const float* __restrict__ bias,
                                              const float* __restrict__ resid,
                                              void* __restrict__ outp,
                                              int M, int N, int K){
  __shared__ bf16_t As[128][40];
  __shared__ bf16_t Bs[128][40];
  const int tid  = threadIdx.x;
  const int lane = tid & 63, wid = tid >> 6;
  const int m0 = blockIdx.x * 128, n0 = blockIdx.y * 128;
  const int wr = (wid >> 1) * 64, wc = (wid & 1) * 64;
  const int fr = lane & 15, kk = (lane >> 4) * 8;
  const int srow = tid >> 2, sseg = (tid & 3) * 8;
  f32x4 acc[4][4];
  #pragma unroll
  for (int m = 0; m < 4; m++)
    #pragma unroll
    for (int n = 0; n < 4; n++) acc[m][n] = (f32x4){0, 0, 0, 0};

  const bf16_t* Arow0 = A  + (size_t)(m0 + srow)      * K + sseg;
  const bf16_t* Arow1 = A  + (size_t)(m0 + srow + 64) * K + sseg;
  const bf16_t* Brow0 = Bt + (size_t)(n0 + srow)      * K + sseg;
  const bf16_t* Brow1 = Bt + (size_t)(n0 + srow + 64) * K + sseg;

  for (int k0 = 0; k0 < K; k0 += 32){
    *(bf16x8*)&As[srow][sseg]      = *(const bf16x8*)(Arow0 + k0);
    *(bf16x8*)&As[srow + 64][sseg] = *(const bf16x8*)(Arow1 + k0);
    *(bf16x8*)&Bs[srow][sseg]      = *(const bf16x8*)(Brow0 + k0);
    *(bf16x8*)&Bs[srow + 64][sseg] = *(const bf16x8*)(Brow1 + k0);
    __syncthreads();
    bf16x8 af[4], bfv[4];
    #pragma unroll
    for (int m = 0; m < 4; m++) af[m]  = *(const bf16x8*)&As[wr + m*16 + fr][kk];
    #pragma unroll
    for (int n = 0; n < 4; n++) bfv[n] = *(const bf16x8*)&Bs[wc + n*16 + fr][kk];
    #pragma unroll
    for (int m = 0; m < 4; m++)
      #pragma unroll
      for (int n = 0; n < 4; n++)
        acc[m][n] = mfma16(af[m], bfv[n], acc[m][n]);
    __syncthreads();
  }

  #pragma unroll
  for (int m = 0; m < 4; m++){
    #pragma unroll
    for (int n = 0; n < 4; n++){
      #pragma unroll
      for (int r = 0; r < 4; r++){
        int row = m0 + wr + m*16 + (lane >> 4) * 4 + r;
        int col = n0 + wc + n*16 + fr;
        float val = acc[m][n][r] + bias[col];
        if constexpr (EPI == 0){
          ((bf16_t*)outp)[(((size_t)(row >> 11) * H_ + (col >> 6)) * S_ + (row & (S_-1))) * DH_ + (col & 63)] = (bf16_t)val;
        } else if constexpr (EPI == 1){
          ((bf16_t*)outp)[(((size_t)(row >> 11) * H_ + (col >> 6)) * DH_ + (col & 63)) * S_ + (row & (S_-1))] = (bf16_t)val;
        } else if constexpr (EPI == 2 || EPI == 4){
          ((float*)outp)[(size_t)row * N + col] = val + resid[(size_t)row * N + col];
        } else {
          ((bf16_t*)outp)[(size_t)row * N + col] = (bf16_t)fmaxf(val, 0.0f);
        }
      }
    }
  }
}

// ---- causal flash attention: Q[bh][s][dh], K[bh][s][dh], Vt[bh][dh][s] -> attn[b][s][h*dh] ----
__global__ __launch_bounds__(256) void attn_k(const bf16_t* __restrict__ Q,
                                              const bf16_t* __restrict__ Kb,
                                              const bf16_t* __restrict__ Vt,
                                              bf16_t* __restrict__ outp){
  __shared__ bf16_t plds[4][16][40];
  const int lane = threadIdx.x & 63, wid = threadIdx.x >> 6;
  const int bh = blockIdx.y;
  const int q0 = blockIdx.x * 64 + wid * 16;
  const int fr = lane & 15, g8 = (lane >> 4) * 8;
  const bf16_t* Qb = Q  + (size_t)bh * S_ * DH_;
  const bf16_t* KB = Kb + (size_t)bh * S_ * DH_;
  const bf16_t* VB = Vt + (size_t)bh * DH_ * S_;
  bf16x8 qf0 = *(const bf16x8*)&Qb[(q0 + fr) * DH_ + g8];
  bf16x8 qf1 = *(const bf16x8*)&Qb[(q0 + fr) * DH_ + 32 + g8];
  f32x4 o[4];
  #pragma unroll
  for (int n = 0; n < 4; n++) o[n] = (f32x4){0, 0, 0, 0};
  float mrun[4], lrun[4];
  #pragma unroll
  for (int r = 0; r < 4; r++){ mrun[r] = -1e30f; lrun[r] = 0.0f; }
  bf16_t* pw = &plds[wid][0][0];
  const int qrow = q0 + (lane >> 4) * 4;

  for (int kv0 = 0; kv0 <= q0 + 15; kv0 += 32){
    bf16x8 kf00 = *(const bf16x8*)&KB[(kv0 + fr) * DH_ + g8];
    bf16x8 kf01 = *(const bf16x8*)&KB[(kv0 + fr) * DH_ + 32 + g8];
    bf16x8 kf10 = *(const bf16x8*)&KB[(kv0 + 16 + fr) * DH_ + g8];
    bf16x8 kf11 = *(const bf16x8*)&KB[(kv0 + 16 + fr) * DH_ + 32 + g8];
    f32x4 sc0 = (f32x4){0,0,0,0}, sc1 = (f32x4){0,0,0,0};
    sc0 = mfma16(qf0, kf00, sc0);
    sc0 = mfma16(qf1, kf01, sc0);
    sc1 = mfma16(qf0, kf10, sc1);
    sc1 = mfma16(qf1, kf11, sc1);
    #pragma unroll
    for (int r = 0; r < 4; r++){
      float a = sc0[r] * 0.125f; if (kv0 + fr > qrow + r)      a = -1e30f;
      float b = sc1[r] * 0.125f; if (kv0 + 16 + fr > qrow + r) b = -1e30f;
      float pm = fmaxf(a, b);
      #pragma unroll
      for (int off = 1; off < 16; off <<= 1) pm = fmaxf(pm, __shfl_xor(pm, off));
      float mnew = fmaxf(mrun[r], pm);
      float scl = __expf(mrun[r] - mnew);
      float e0 = __expf(a - mnew);
      float e1 = __expf(b - mnew);
      float rs = e0 + e1;
      #pragma unroll
      for (int off = 1; off < 16; off <<= 1) rs += __shfl_xor(rs, off);
      lrun[r] = lrun[r] * scl + rs;
      mrun[r] = mnew;
      #pragma unroll
      for (int n = 0; n < 4; n++) o[n][r] *= scl;
      pw[((lane >> 4) * 4 + r) * 40 + fr]      = (bf16_t)e0;
      pw[((lane >> 4) * 4 + r) * 40 + 16 + fr] = (bf16_t)e1;
    }
    bf16x8 pa = *(const bf16x8*)&pw[fr * 40 + g8];
    #pragma unroll
    for (int n = 0; n < 4; n++){
      bf16x8 vf = *(const bf16x8*)&VB[(n * 16 + fr) * S_ + kv0 + g8];
      o[n] = mfma16(pa, vf, o[n]);
    }
  }
  const int b = bh >> 4, h = bh & 15;
  #pragma unroll
  for (int n = 0; n < 4; n++)
    #pragma unroll
    for (int r = 0; r < 4; r++){
      float val = o[n][r] / lrun[r];
      outp[((size_t)b * S_ + qrow + r) * D_ + h * DH_ + n * 16 + fr] = (bf16_t)val;
    }
}

extern "C" void kernel_launch(void* const* d_in, const int* in_sizes, int n_in,
                              void* d_out, int out_size, void* d_ws, size_t ws_size,
                              hipStream_t stream){
  (void)in_sizes; (void)n_in; (void)out_size; (void)ws_size;
  const float* X  = (const float*)d_in[0];
  // d_in[1] = attention_mask (always causal tril) — handled analytically
  const float* g1 = (const float*)d_in[2];
  const float* o1 = (const float*)d_in[3];
  const float* g2 = (const float*)d_in[4];
  const float* o2 = (const float*)d_in[5];
  const float* Wq = (const float*)d_in[6];
  const float* bq = (const float*)d_in[7];
  const float* Wk = (const float*)d_in[8];
  const float* bk = (const float*)d_in[9];
  const float* Wv = (const float*)d_in[10];
  const float* bv = (const float*)d_in[11];
  const float* W0 = (const float*)d_in[12];
  const float* b0 = (const float*)d_in[13];
  const float* W1 = (const float*)d_in[14];
  const float* b1 = (const float*)d_in[15];
  const float* W2 = (const float*)d_in[16];
  const float* b2 = (const float*)d_in[17];

  char* ws = (char*)d_ws;
  const size_t MB = 1024 * 1024;
  bf16_t* Xn1  = (bf16_t*)(ws + 0);        // 8MB (dead after V gemm)
  bf16_t* attn = (bf16_t*)(ws + 0);        // reuses Xn1 slot
  bf16_t* Wqt  = (bf16_t*)(ws + 8  * MB);  // 2MB
  bf16_t* Wkt  = (bf16_t*)(ws + 10 * MB);  // 2MB
  bf16_t* Wvt  = (bf16_t*)(ws + 12 * MB);  // 2MB
  bf16_t* W0t  = (bf16_t*)(ws + 14 * MB);  // 2MB
  bf16_t* W1t  = (bf16_t*)(ws + 16 * MB);  // 8MB
  bf16_t* W2t  = (bf16_t*)(ws + 24 * MB);  // 8MB
  bf16_t* Qb   = (bf16_t*)(ws + 32 * MB);  // 8MB
  bf16_t* Kbuf = (bf16_t*)(ws + 40 * MB);  // 8MB
  bf16_t* Vtb  = (bf16_t*)(ws + 48 * MB);  // 8MB
  bf16_t* hid  = (bf16_t*)(ws + 32 * MB);  // 32MB, reuses Q/K/Vt after attention
  float*  X2   = (float*) (ws + 64 * MB);  // 16MB
  bf16_t* Xn2  = (bf16_t*)(ws + 80 * MB);  // 8MB  (total 88MB)

  dim3 b256(256);
  repack_qkv_k<<<dim3(D_*D_/256), b256, 0, stream>>>(Wq, Wqt);
  repack_qkv_k<<<dim3(D_*D_/256), b256, 0, stream>>>(Wk, Wkt);
  repack_qkv_k<<<dim3(D_*D_/256), b256, 0, stream>>>(Wv, Wvt);
  transpose_f2b_k<<<dim3(D_/32,  D_/32),  dim3(32,8), 0, stream>>>(W0, W0t, D_,  D_);
  transpose_f2b_k<<<dim3(D_/32,  DF_/32), dim3(32,8), 0, stream>>>(W1, W1t, D_,  DF_);
  transpose_f2b_k<<<dim3(DF_/32, D_/32),  dim3(32,8), 0, stream>>>(W2, W2t, DF_, D_);
  ln_k<<<dim3(M_), b256, 0, stream>>>(X, g1, o1, Xn1);
  gemm_k<0><<<dim3(M_/128, D_/128),  b256, 0, stream>>>(Xn1, Wqt, bq, nullptr, Qb,   M_, D_,  D_);
  gemm_k<0><<<dim3(M_/128, D_/128),  b256, 0, stream>>>(Xn1, Wkt, bk, nullptr, Kbuf, M_, D_,  D_);
  gemm_k<1><<<dim3(M_/128, D_/128),  b256, 0, stream>>>(Xn1, Wvt, bv, nullptr, Vtb,  M_, D_,  D_);
  attn_k<<<dim3(S_/64, B_*H_), b256, 0, stream>>>(Qb, Kbuf, Vtb, attn);
  gemm_k<2><<<dim3(M_/128, D_/128),  b256, 0, stream>>>(attn, W0t, b0, X,  X2, M_, D_,  D_);
  ln_k<<<dim3(M_), b256, 0, stream>>>(X2, g2, o2, Xn2);
  gemm_k<3><<<dim3(M_/128, DF_/128), b256, 0, stream>>>(Xn2, W1t, b1, nullptr, hid, M_, DF_, D_);
  gemm_k<4><<<dim3(M_/128, D_/128),  b256, 0, stream>>>(hid, W2t, b2, X2, (float*)d_out, M_, D_, DF_);
}

// Round 4
// 489.913 us; speedup vs baseline: 1.0700x; 1.0700x over previous
//
#include <hip/hip_runtime.h>

#define B_ 2
#define S_ 2048
#define D_ 1024
#define H_ 16
#define DH_ 64
#define DF_ 4096
#define M_ (B_*S_)   // 4096

typedef __bf16 bf16_t;
typedef __attribute__((ext_vector_type(4))) __bf16 bf16x4;
typedef __attribute__((ext_vector_type(8))) __bf16 bf16x8;
typedef __attribute__((ext_vector_type(4))) float f32x4;

__device__ inline f32x4 mfma16(bf16x8 a, bf16x8 b, f32x4 c){
  return __builtin_amdgcn_mfma_f32_16x16x32_bf16(a, b, c, 0, 0, 0);
}

__device__ inline void glds16(const void* g, void* l){
  __builtin_amdgcn_global_load_lds((const __attribute__((address_space(1))) void*)g,
                                   (__attribute__((address_space(3))) void*)l, 16, 0, 0);
}

// ---- repack Wq/Wk/Wv [H][D][DH] fp32 -> [N=h*DH+dh][K=d] bf16 ----
__global__ __launch_bounds__(256) void repack_qkv_k(const float* __restrict__ w,
                                                    bf16_t* __restrict__ o){
  int idx = blockIdx.x * 256 + threadIdx.x;     // over D_*D_
  int n = idx >> 10, d = idx & (D_ - 1);
  o[idx] = (bf16_t)w[((size_t)(n >> 6) * D_ + d) * DH_ + (n & 63)];
}

// ---- transpose fp32 [K][N] -> bf16 [N][K] ----
__global__ __launch_bounds__(256) void transpose_f2b_k(const float* __restrict__ in,
                                                       bf16_t* __restrict__ out,
                                                       int K, int N){
  __shared__ float t[32][33];
  int kb = blockIdx.x * 32, nb = blockIdx.y * 32;
  for (int i = threadIdx.y; i < 32; i += 8)
    t[i][threadIdx.x] = in[(size_t)(kb + i) * N + nb + threadIdx.x];
  __syncthreads();
  for (int i = threadIdx.y; i < 32; i += 8)
    out[(size_t)(nb + i) * K + kb + threadIdx.x] = (bf16_t)t[threadIdx.x][i];
}

// ---- LayerNorm fp32 row -> bf16 ----
__global__ __launch_bounds__(256) void ln_k(const float* __restrict__ x,
                                            const float* __restrict__ g,
                                            const float* __restrict__ o,
                                            bf16_t* __restrict__ out){
  int row = blockIdx.x;
  const float* xr = x + (size_t)row * D_;
  f32x4 v = *((const f32x4*)xr + threadIdx.x);
  float s  = v[0] + v[1] + v[2] + v[3];
  float sq = v[0]*v[0] + v[1]*v[1] + v[2]*v[2] + v[3]*v[3];
  #pragma unroll
  for (int off = 1; off < 64; off <<= 1){
    s  += __shfl_xor(s, off);
    sq += __shfl_xor(sq, off);
  }
  __shared__ float ss[4], ssq[4];
  int wid = threadIdx.x >> 6;
  if ((threadIdx.x & 63) == 0){ ss[wid] = s; ssq[wid] = sq; }
  __syncthreads();
  s  = ss[0] + ss[1] + ss[2] + ss[3];
  sq = ssq[0] + ssq[1] + ssq[2] + ssq[3];
  float mean = s * (1.0f / D_);
  float var  = fmaxf(sq * (1.0f / D_) - mean * mean, 0.0f);
  float inv  = 1.0f / (sqrtf(var) + 1e-9f);
  int c = threadIdx.x * 4;
  bf16_t* orow = out + (size_t)row * D_;
  #pragma unroll
  for (int j = 0; j < 4; j++)
    orow[c + j] = (bf16_t)(g[c + j] * ((v[j] - mean) * inv) + o[c + j]);
}

// ---- GEMM: C[M,N] = A[M,K](bf16) @ Bt[N,K](bf16)^T, global_load_lds staging ----
// EPI 0: fused QKV -> Q/K [bh][s][dh], V^T [bh][dh][s]   (outp = QKV base, bias = concat[3072])
// EPI 2: fp32 out = acc + bias + resid
// EPI 3: bf16 out = relu(acc + bias)
template<int EPI>
__global__ __launch_bounds__(256) void gemm_k(const bf16_t* __restrict__ A,
                                              const bf16_t* __restrict__ Bt,
                                              const float* __restrict__ bias,
                                              const float* __restrict__ resid,
                                              void* __restrict__ outp,
                                              int M, int N, int K){
  __shared__ bf16_t As[128][32];
  __shared__ bf16_t Bs[128][32];
  const int tid  = threadIdx.x;
  const int lane = tid & 63, wid = tid >> 6;
  const int m0 = blockIdx.x * 128, n0 = blockIdx.y * 128;
  const int wr = (wid >> 1) * 64, wc = (wid & 1) * 64;
  const int fr = lane & 15, kk = (lane >> 4) * 8;
  const int srow = tid >> 2, scol = (tid & 3) * 8;   // staging row / col (elements)
  f32x4 acc[4][4];
  #pragma unroll
  for (int m = 0; m < 4; m++)
    #pragma unroll
    for (int n = 0; n < 4; n++) acc[m][n] = (f32x4){0, 0, 0, 0};

  const bf16_t* Ag = A  + (size_t)(m0 + srow) * K + scol;
  const bf16_t* Bg = Bt + (size_t)(n0 + srow) * K + scol;
  char* ldsA = (char*)&As[0][0] + tid * 16;
  char* ldsB = (char*)&Bs[0][0] + tid * 16;

  for (int k0 = 0; k0 < K; k0 += 32){
    glds16(Ag + k0,                  ldsA);
    glds16(Ag + (size_t)64 * K + k0, ldsA + 4096);
    glds16(Bg + k0,                  ldsB);
    glds16(Bg + (size_t)64 * K + k0, ldsB + 4096);
    __syncthreads();
    bf16x8 af[4], bfv[4];
    #pragma unroll
    for (int m = 0; m < 4; m++) af[m]  = *(const bf16x8*)&As[wr + m*16 + fr][kk];
    #pragma unroll
    for (int n = 0; n < 4; n++) bfv[n] = *(const bf16x8*)&Bs[wc + n*16 + fr][kk];
    #pragma unroll
    for (int m = 0; m < 4; m++)
      #pragma unroll
      for (int n = 0; n < 4; n++)
        acc[m][n] = mfma16(af[m], bfv[n], acc[m][n]);
    __syncthreads();
  }

  #pragma unroll
  for (int m = 0; m < 4; m++){
    #pragma unroll
    for (int n = 0; n < 4; n++){
      #pragma unroll
      for (int r = 0; r < 4; r++){
        int row = m0 + wr + m*16 + (lane >> 4) * 4 + r;
        int col = n0 + wc + n*16 + fr;
        if constexpr (EPI == 0){
          int seg = col >> 10, c = col & 1023;
          int h = c >> 6, dh = c & 63;
          int b = row >> 11, sidx = row & (S_ - 1);
          float val = acc[m][n][r] + bias[col];
          bf16_t* base = (bf16_t*)outp + (size_t)seg * M_ * D_;
          if (seg < 2)
            base[(((size_t)b * H_ + h) * S_ + sidx) * DH_ + dh] = (bf16_t)val;
          else
            base[(((size_t)b * H_ + h) * DH_ + dh) * S_ + sidx] = (bf16_t)val;
        } else if constexpr (EPI == 2){
          float val = acc[m][n][r] + bias[col];
          ((float*)outp)[(size_t)row * N + col] = val + resid[(size_t)row * N + col];
        } else {
          float val = acc[m][n][r] + bias[col];
          ((bf16_t*)outp)[(size_t)row * N + col] = (bf16_t)fmaxf(val, 0.0f);
        }
      }
    }
  }
}

// ---- causal flash attention, swapped-QK^T: lane owns one q-row's scores ----
// Q,K [bh][s][dh], Vt [bh][dh][s] -> attn [b][s][h*dh]
// R3: epilogue transpose in its own per-wave [16][72] buffer (fixes the
//     inter-wave LDS overrun race latent since R1).
// R4 BUGFIX: PV operand order. The whole pipeline is TRANSPOSED (S^T, O^T with
//     col=q=l15): rescale by scl, division by lrun, and the epilogue all index
//     q by l15. PV must therefore be mfma(A=V^T, B=P^T) -> O^T. R2/R3 passed
//     (pa, vf) which computes O in NORMAL orientation -> wrong row's lrun and
//     a scrambled epilogue. Deterministic; explains identical absmax 3.0547
//     in R2 and R3.
__global__ __launch_bounds__(256) void attn_k(const bf16_t* __restrict__ Q,
                                              const bf16_t* __restrict__ Kb,
                                              const bf16_t* __restrict__ Vt,
                                              bf16_t* __restrict__ outp){
  __shared__ bf16_t plds[4][16][40];   // per-wave P tile [q=16][k_local=32] pad 40
  __shared__ bf16_t tlds[4][16][72];   // per-wave epilogue transpose [q=16][dh=64] pad 72
  const int lane = threadIdx.x & 63, wid = threadIdx.x >> 6;
  const int bh = blockIdx.y;
  const int qb = gridDim.x - 1 - blockIdx.x;       // heavy tiles launch first
  const int q0 = qb * 64 + wid * 16;
  const int l15 = lane & 15, g = lane >> 4, g8 = g * 8;
  const bf16_t* Qp = Q  + (size_t)bh * S_ * DH_;
  const bf16_t* Kp = Kb + (size_t)bh * S_ * DH_;
  const bf16_t* Vp = Vt + (size_t)bh * DH_ * S_;
  // Q as B-operand: col = l15 = q row, k-dim = dh
  bf16x8 qf0 = *(const bf16x8*)&Qp[(q0 + l15) * DH_ + g8];
  bf16x8 qf1 = *(const bf16x8*)&Qp[(q0 + l15) * DH_ + 32 + g8];
  f32x4 o[4];
  #pragma unroll
  for (int t = 0; t < 4; t++) o[t] = (f32x4){0, 0, 0, 0};
  float mrun = -1e30f, lrun = 0.0f;
  const int qrow = q0 + l15;                       // this lane's q row
  bf16_t* pw = &plds[wid][0][0];

  for (int kv0 = 0; kv0 <= q0 + 15; kv0 += 32){
    // K as A-operand: row = l15 = k row, k-dim = dh
    bf16x8 kf00 = *(const bf16x8*)&Kp[(kv0 + l15) * DH_ + g8];
    bf16x8 kf01 = *(const bf16x8*)&Kp[(kv0 + l15) * DH_ + 32 + g8];
    bf16x8 kf10 = *(const bf16x8*)&Kp[(kv0 + 16 + l15) * DH_ + g8];
    bf16x8 kf11 = *(const bf16x8*)&Kp[(kv0 + 16 + l15) * DH_ + 32 + g8];
    f32x4 s0 = (f32x4){0,0,0,0}, s1 = (f32x4){0,0,0,0};
    s0 = mfma16(kf00, qf0, s0);
    s0 = mfma16(kf01, qf1, s0);
    s1 = mfma16(kf10, qf0, s1);
    s1 = mfma16(kf11, qf1, s1);
    // lane holds S^T: col=q (l15), row=k = kv0 + g*4 + r (+16 for s1)
    const int kb = kv0 + g * 4;
    float a[8];
    #pragma unroll
    for (int r = 0; r < 4; r++){
      a[r]     = (kb + r      <= qrow) ? s0[r] * 0.125f : -1e30f;
      a[4 + r] = (kb + 16 + r <= qrow) ? s1[r] * 0.125f : -1e30f;
    }
    float pm = fmaxf(fmaxf(fmaxf(a[0],a[1]), fmaxf(a[2],a[3])),
                     fmaxf(fmaxf(a[4],a[5]), fmaxf(a[6],a[7])));
    pm = fmaxf(pm, __shfl_xor(pm, 16));
    pm = fmaxf(pm, __shfl_xor(pm, 32));
    float mnew = fmaxf(mrun, pm);
    float scl = __expf(mrun - mnew);
    float e[8], rs = 0.0f;
    #pragma unroll
    for (int i = 0; i < 8; i++){ e[i] = __expf(a[i] - mnew); rs += e[i]; }
    rs += __shfl_xor(rs, 16);
    rs += __shfl_xor(rs, 32);
    lrun = lrun * scl + rs;
    mrun = mnew;
    #pragma unroll
    for (int t = 0; t < 4; t++) o[t] *= scl;
    // P -> LDS as [q][k_local] (pad 40): lane writes 2x bf16x4
    bf16x4 p0, p1;
    #pragma unroll
    for (int r = 0; r < 4; r++){ p0[r] = (bf16_t)e[r]; p1[r] = (bf16_t)e[4 + r]; }
    *(bf16x4*)&pw[l15 * 40 + g * 4]      = p0;
    *(bf16x4*)&pw[l15 * 40 + 16 + g * 4] = p1;
    // P^T as B-operand: col = l15 = q, k-dim = kv local
    bf16x8 pa = *(const bf16x8*)&pw[l15 * 40 + g8];
    #pragma unroll
    for (int t = 0; t < 4; t++){
      // V^T as A-operand: row = l15 = dh (tile t), k-dim = kv
      bf16x8 vf = *(const bf16x8*)&Vp[(t * 16 + l15) * S_ + kv0 + g8];
      o[t] = mfma16(vf, pa, o[t]);   // O^T: col=q (l15), row = dh local   [R4 fix]
    }
  }

  // epilogue: O^T -> O via wave-local LDS transpose, coalesced store
  float inv = 1.0f / lrun;
  bf16_t* tw = &tlds[wid][0][0];                    // [16 q][72 dh-padded]
  #pragma unroll
  for (int t = 0; t < 4; t++){
    bf16x4 w;
    #pragma unroll
    for (int r = 0; r < 4; r++) w[r] = (bf16_t)(o[t][r] * inv);
    *(bf16x4*)&tw[l15 * 72 + t * 16 + g * 4] = w;
  }
  const int b = bh >> 4, h = bh & 15;
  const int rr = lane >> 3, cc = (lane & 7) * 8;
  bf16x8 r0 = *(const bf16x8*)&tw[rr * 72 + cc];
  bf16x8 r1 = *(const bf16x8*)&tw[(rr + 8) * 72 + cc];
  *(bf16x8*)&outp[((size_t)b * S_ + q0 + rr) * D_ + h * 64 + cc]     = r0;
  *(bf16x8*)&outp[((size_t)b * S_ + q0 + rr + 8) * D_ + h * 64 + cc] = r1;
}

extern "C" void kernel_launch(void* const* d_in, const int* in_sizes, int n_in,
                              void* d_out, int out_size, void* d_ws, size_t ws_size,
                              hipStream_t stream){
  (void)in_sizes; (void)n_in; (void)out_size; (void)ws_size;
  const float* X  = (const float*)d_in[0];
  // d_in[1] = attention_mask (always causal tril) — handled analytically
  const float* g1 = (const float*)d_in[2];
  const float* o1 = (const float*)d_in[3];
  const float* g2 = (const float*)d_in[4];
  const float* o2 = (const float*)d_in[5];
  const float* Wq = (const float*)d_in[6];
  const float* bq = (const float*)d_in[7];
  const float* Wk = (const float*)d_in[8];
  const float* bk = (const float*)d_in[9];
  const float* Wv = (const float*)d_in[10];
  const float* bv = (const float*)d_in[11];
  const float* W0 = (const float*)d_in[12];
  const float* b0 = (const float*)d_in[13];
  const float* W1 = (const float*)d_in[14];
  const float* b1 = (const float*)d_in[15];
  const float* W2 = (const float*)d_in[16];
  const float* b2 = (const float*)d_in[17];

  char* ws = (char*)d_ws;
  const size_t MB = 1024 * 1024;
  bf16_t* Xn1    = (bf16_t*)(ws + 0);        // 8MB; reused as attn out later
  bf16_t* attn   = (bf16_t*)(ws + 0);
  bf16_t* Wqkvt  = (bf16_t*)(ws + 8  * MB);  // 6MB  [3072][1024]
  bf16_t* W0t    = (bf16_t*)(ws + 14 * MB);  // 2MB
  bf16_t* W1t    = (bf16_t*)(ws + 16 * MB);  // 8MB
  bf16_t* W2t    = (bf16_t*)(ws + 24 * MB);  // 8MB
  bf16_t* QKV    = (bf16_t*)(ws + 32 * MB);  // 24MB: Q@32, K@40, V^T@48
  bf16_t* Qb     = QKV;
  bf16_t* Kbuf   = QKV + (size_t)M_ * D_;
  bf16_t* Vtb    = QKV + (size_t)2 * M_ * D_;
  bf16_t* hid    = (bf16_t*)(ws + 32 * MB);  // 32MB, reuses QKV after attention
  float*  qkvbias= (float*)(ws + 60 * MB);   // 12KB; dead before hid's region is written
  float*  X2     = (float*) (ws + 64 * MB);  // 16MB
  bf16_t* Xn2    = (bf16_t*)(ws + 80 * MB);  // 8MB  (total 88MB)

  dim3 b256(256);
  repack_qkv_k<<<dim3(D_*D_/256), b256, 0, stream>>>(Wq, Wqkvt);
  repack_qkv_k<<<dim3(D_*D_/256), b256, 0, stream>>>(Wk, Wqkvt + (size_t)D_*D_);
  repack_qkv_k<<<dim3(D_*D_/256), b256, 0, stream>>>(Wv, Wqkvt + (size_t)2*D_*D_);
  transpose_f2b_k<<<dim3(D_/32,  D_/32),  dim3(32,8), 0, stream>>>(W0, W0t, D_,  D_);
  transpose_f2b_k<<<dim3(D_/32,  DF_/32), dim3(32,8), 0, stream>>>(W1, W1t, D_,  DF_);
  transpose_f2b_k<<<dim3(DF_/32, D_/32),  dim3(32,8), 0, stream>>>(W2, W2t, DF_, D_);
  hipMemcpyAsync(qkvbias,        bq, D_*sizeof(float), hipMemcpyDeviceToDevice, stream);
  hipMemcpyAsync(qkvbias + D_,   bk, D_*sizeof(float), hipMemcpyDeviceToDevice, stream);
  hipMemcpyAsync(qkvbias + 2*D_, bv, D_*sizeof(float), hipMemcpyDeviceToDevice, stream);
  ln_k<<<dim3(M_), b256, 0, stream>>>(X, g1, o1, Xn1);
  gemm_k<0><<<dim3(M_/128, 3*D_/128), b256, 0, stream>>>(Xn1, Wqkvt, qkvbias, nullptr, QKV, M_, 3*D_, D_);
  attn_k<<<dim3(S_/64, B_*H_), b256, 0, stream>>>(Qb, Kbuf, Vtb, attn);
  gemm_k<2><<<dim3(M_/128, D_/128),  b256, 0, stream>>>(attn, W0t, b0, X,  X2, M_, D_,  D_);
  ln_k<<<dim3(M_), b256, 0, stream>>>(X2, g2, o2, Xn2);
  gemm_k<3><<<dim3(M_/128, DF_/128), b256, 0, stream>>>(Xn2, W1t, b1, nullptr, hid, M_, DF_, D_);
  gemm_k<2><<<dim3(M_/128, D_/128),  b256, 0, stream>>>(hid, W2t, b2, X2, (float*)d_out, M_, D_, DF_);
}